// Round 1
// baseline (118.251 us; speedup 1.0000x reference)
//
#include <hip/hip_runtime.h>

// IntegerNeuron: spiking-neuron scan over T with soft reset.
// x_accum [T,B,C,H,W] f32; per-channel scale/bias/vth [C]; tau scalar; is_first_layer int.
// out = spikes [T,B,C,H,W] f32 (0.0 or 1.0).
//
// T recurrence is elementwise over B*C*H*W positions -> one thread owns 4
// positions (float4), carries mem in registers across all 8 steps.
// Memory-bound: 256 MiB read + 256 MiB write => ~85us floor at 6.3 TB/s.
//
// Bit-exactness vs numpy f32 reference is mandatory (binary output):
//  - rintf (half-to-even) to match np.round
//  - explicit __fmul_rn/__fadd_rn so no FMA contraction changes mem rounding
//  - op order matches reference exactly: ((mem + x*tau) + bias_scaled)

#define T_STEPS 8
#define C_CH    256
#define HW      1024
#define EPS_F   1e-12f

__global__ __launch_bounds__(256) void integer_neuron_kernel(
    const float* __restrict__ x,          // [T, B*C*HW]
    const float* __restrict__ prev_scale, // [C]
    const float* __restrict__ prev_bias,  // [C]
    const float* __restrict__ vth,        // [C]
    const float* __restrict__ tau_p,      // [1]
    const int*   __restrict__ is_first_p, // [1]
    float* __restrict__ out,              // [T, B*C*HW]
    long long n_planes)                   // B*C
{
    const float tau      = tau_p[0];
    const int   is_first = is_first_p[0];
    // drive = x_accum if is_first else x_accum * tau. Multiplying by exactly
    // 1.0f is bit-identical to the identity for finite inputs.
    const float drive_mul = is_first ? 1.0f : tau;

    const long long plane = (long long)blockIdx.x;   // one block per (b,c) plane of HW=1024
    const int c = (int)(plane % C_CH);

    // Block-uniform per-channel constants; exact reference op order:
    //   round(b*tau/(s+EPS)), round(v*tau/(s+EPS)) with round = half-to-even.
    const float denom      = __fadd_rn(prev_scale[c], EPS_F);
    const float bias_scaled = rintf(__fdiv_rn(__fmul_rn(prev_bias[c], tau), denom));
    const float vth_scaled  = rintf(__fdiv_rn(__fmul_rn(vth[c],       tau), denom));

    const long long N    = n_planes * (long long)HW;             // stride per time step
    const long long base = plane * (long long)HW + (long long)threadIdx.x * 4;

    float4 mem = make_float4(0.0f, 0.0f, 0.0f, 0.0f);

    #pragma unroll
    for (int t = 0; t < T_STEPS; ++t) {
        const long long off = (long long)t * N + base;
        const float4 xv = *reinterpret_cast<const float4*>(x + off);

        float4 sp;

        // component x
        mem.x = __fadd_rn(__fadd_rn(mem.x, __fmul_rn(xv.x, drive_mul)), bias_scaled);
        sp.x  = (mem.x >= vth_scaled) ? 1.0f : 0.0f;
        mem.x = __fsub_rn(mem.x, __fmul_rn(sp.x, vth_scaled));
        // component y
        mem.y = __fadd_rn(__fadd_rn(mem.y, __fmul_rn(xv.y, drive_mul)), bias_scaled);
        sp.y  = (mem.y >= vth_scaled) ? 1.0f : 0.0f;
        mem.y = __fsub_rn(mem.y, __fmul_rn(sp.y, vth_scaled));
        // component z
        mem.z = __fadd_rn(__fadd_rn(mem.z, __fmul_rn(xv.z, drive_mul)), bias_scaled);
        sp.z  = (mem.z >= vth_scaled) ? 1.0f : 0.0f;
        mem.z = __fsub_rn(mem.z, __fmul_rn(sp.z, vth_scaled));
        // component w
        mem.w = __fadd_rn(__fadd_rn(mem.w, __fmul_rn(xv.w, drive_mul)), bias_scaled);
        sp.w  = (mem.w >= vth_scaled) ? 1.0f : 0.0f;
        mem.w = __fsub_rn(mem.w, __fmul_rn(sp.w, vth_scaled));

        *reinterpret_cast<float4*>(out + off) = sp;
    }
}

extern "C" void kernel_launch(void* const* d_in, const int* in_sizes, int n_in,
                              void* d_out, int out_size, void* d_ws, size_t ws_size,
                              hipStream_t stream) {
    const float* x          = (const float*)d_in[0]; // [T,B,C,H,W]
    const float* prev_scale = (const float*)d_in[1]; // [C]
    const float* prev_bias  = (const float*)d_in[2]; // [C]
    const float* vth        = (const float*)d_in[3]; // [C]
    const float* tau        = (const float*)d_in[4]; // [1]
    const int*   is_first   = (const int*)d_in[5];   // [1]
    float* out = (float*)d_out;

    // total elems = T * n_planes * HW; n_planes = B*C
    const long long total    = (long long)out_size;
    const long long n_planes = total / ((long long)T_STEPS * HW);

    dim3 grid((unsigned)n_planes);  // 8192 blocks, one HW-plane each
    dim3 block(256);                // 256 threads * float4 = 1024 elems
    integer_neuron_kernel<<<grid, block, 0, stream>>>(
        x, prev_scale, prev_bias, vth, tau, is_first, out, n_planes);
}

// Round 2
// 100.142 us; speedup vs baseline: 1.1808x; 1.1808x over previous
//
#include <hip/hip_runtime.h>

// IntegerNeuron: spiking-neuron scan over T with soft reset.
// x_accum [T,B,C,H,W] f32; per-channel scale/bias/vth [C]; tau scalar; is_first_layer int.
// out = spikes [T,B,C,H,W] f32 (0.0 or 1.0).
//
// Pure streaming op (zero reuse): 256 MiB read + 256 MiB write.
// R1: float4 + reg-carried mem -> 118us (4.5 TB/s).
// R2: non-temporal loads/stores to bypass L1/L2/L3 allocation -- fill kernel
//     shows pure streams reach 6.8-7.0 TB/s on this chip; NT removes the
//     cache-pollution cost of pushing 512 MiB through a 32 MiB L2.
//
// Bit-exactness vs numpy f32 reference is mandatory (binary output):
//  - rintf (half-to-even) to match np.round
//  - explicit __fmul_rn/__fadd_rn so no FMA contraction changes mem rounding
//  - op order matches reference exactly: ((mem + x*tau) + bias_scaled)

#define T_STEPS 8
#define C_CH    256
#define HW      1024
#define EPS_F   1e-12f

typedef float v4f __attribute__((ext_vector_type(4)));

__global__ __launch_bounds__(256) void integer_neuron_kernel(
    const float* __restrict__ x,          // [T, B*C*HW]
    const float* __restrict__ prev_scale, // [C]
    const float* __restrict__ prev_bias,  // [C]
    const float* __restrict__ vth,        // [C]
    const float* __restrict__ tau_p,      // [1]
    const int*   __restrict__ is_first_p, // [1]
    float* __restrict__ out,              // [T, B*C*HW]
    long long n_planes)                   // B*C
{
    const float tau      = tau_p[0];
    const int   is_first = is_first_p[0];
    // drive = x_accum if is_first else x_accum * tau. Multiplying by exactly
    // 1.0f is bit-identical to the identity for finite inputs.
    const float drive_mul = is_first ? 1.0f : tau;

    const long long plane = (long long)blockIdx.x;   // one block per (b,c) plane of HW=1024
    const int c = (int)(plane % C_CH);

    // Block-uniform per-channel constants; exact reference op order:
    //   round(b*tau/(s+EPS)), round(v*tau/(s+EPS)) with round = half-to-even.
    const float denom       = __fadd_rn(prev_scale[c], EPS_F);
    const float bias_scaled = rintf(__fdiv_rn(__fmul_rn(prev_bias[c], tau), denom));
    const float vth_scaled  = rintf(__fdiv_rn(__fmul_rn(vth[c],       tau), denom));

    const long long N    = n_planes * (long long)HW;             // stride per time step
    const long long base = plane * (long long)HW + (long long)threadIdx.x * 4;

    float mx = 0.0f, my = 0.0f, mz = 0.0f, mw = 0.0f;

    #pragma unroll
    for (int t = 0; t < T_STEPS; ++t) {
        const long long off = (long long)t * N + base;
        const v4f xv = __builtin_nontemporal_load(
            reinterpret_cast<const v4f*>(x + off));

        v4f sp;

        // component 0
        mx    = __fadd_rn(__fadd_rn(mx, __fmul_rn(xv.x, drive_mul)), bias_scaled);
        sp.x  = (mx >= vth_scaled) ? 1.0f : 0.0f;
        mx    = __fsub_rn(mx, __fmul_rn(sp.x, vth_scaled));
        // component 1
        my    = __fadd_rn(__fadd_rn(my, __fmul_rn(xv.y, drive_mul)), bias_scaled);
        sp.y  = (my >= vth_scaled) ? 1.0f : 0.0f;
        my    = __fsub_rn(my, __fmul_rn(sp.y, vth_scaled));
        // component 2
        mz    = __fadd_rn(__fadd_rn(mz, __fmul_rn(xv.z, drive_mul)), bias_scaled);
        sp.z  = (mz >= vth_scaled) ? 1.0f : 0.0f;
        mz    = __fsub_rn(mz, __fmul_rn(sp.z, vth_scaled));
        // component 3
        mw    = __fadd_rn(__fadd_rn(mw, __fmul_rn(xv.w, drive_mul)), bias_scaled);
        sp.w  = (mw >= vth_scaled) ? 1.0f : 0.0f;
        mw    = __fsub_rn(mw, __fmul_rn(sp.w, vth_scaled));

        __builtin_nontemporal_store(sp, reinterpret_cast<v4f*>(out + off));
    }
}

extern "C" void kernel_launch(void* const* d_in, const int* in_sizes, int n_in,
                              void* d_out, int out_size, void* d_ws, size_t ws_size,
                              hipStream_t stream) {
    const float* x          = (const float*)d_in[0]; // [T,B,C,H,W]
    const float* prev_scale = (const float*)d_in[1]; // [C]
    const float* prev_bias  = (const float*)d_in[2]; // [C]
    const float* vth        = (const float*)d_in[3]; // [C]
    const float* tau        = (const float*)d_in[4]; // [1]
    const int*   is_first   = (const int*)d_in[5];   // [1]
    float* out = (float*)d_out;

    // total elems = T * n_planes * HW; n_planes = B*C
    const long long total    = (long long)out_size;
    const long long n_planes = total / ((long long)T_STEPS * HW);

    dim3 grid((unsigned)n_planes);  // 8192 blocks, one HW-plane each
    dim3 block(256);                // 256 threads * float4 = 1024 elems
    integer_neuron_kernel<<<grid, block, 0, stream>>>(
        x, prev_scale, prev_bias, vth, tau, is_first, out, n_planes);
}